// Round 10
// baseline (298.926 us; speedup 1.0000x reference)
//
#include <hip/hip_runtime.h>

#define N_NODES 50000
#define N_EDGES 800000
#define D 128
#define NLAYER 4
#define NGRAPH 128
#define GDIM (5 * D) // 640
#define NBUCK 196    // dst>>8 buckets

typedef __attribute__((ext_vector_type(8))) short bf16x8;
typedef __attribute__((ext_vector_type(4))) float f32x4;

__device__ __forceinline__ float b2f(unsigned short u) {
    return __uint_as_float(((unsigned)u) << 16);
}
__device__ __forceinline__ unsigned short f2b(float f) {
    unsigned u = __float_as_uint(f);
    unsigned r = (u + 0x7fffu + ((u >> 16) & 1u)) >> 16; // round-to-nearest-even
    return (unsigned short)r;
}

// ---------------- CSR build ----------------

__global__ void k_count(const int* __restrict__ edst, int* __restrict__ cnt) {
    int e = blockIdx.x * 256 + threadIdx.x;
    if (e < N_EDGES) atomicAdd(&cnt[edst[e]], 1);
}

__global__ void k_scanA(const int* __restrict__ cnt, int* __restrict__ offs,
                        int* __restrict__ chunkSum) {
    __shared__ int lds[256];
    int tid = threadIdx.x;
    int base = blockIdx.x * 1024 + tid * 4;
    int v[4];
    int s = 0;
#pragma unroll
    for (int j = 0; j < 4; ++j) {
        int idx = base + j;
        v[j] = (idx < N_NODES) ? cnt[idx] : 0;
        s += v[j];
    }
    lds[tid] = s;
    __syncthreads();
    int t = s;
    for (int off = 1; off < 256; off <<= 1) {
        int add = (tid >= off) ? lds[tid - off] : 0;
        __syncthreads();
        t += add;
        lds[tid] = t;
        __syncthreads();
    }
    int run = t - s;
#pragma unroll
    for (int j = 0; j < 4; ++j) {
        int idx = base + j;
        if (idx < N_NODES) offs[idx] = run;
        run += v[j];
    }
    if (tid == 255) chunkSum[blockIdx.x] = t;
}

__global__ void k_scanB(const int* __restrict__ chunkSum, int* __restrict__ chunkOff,
                        int nc) {
    __shared__ int lds[64];
    int tid = threadIdx.x;
    int v = (tid < nc) ? chunkSum[tid] : 0;
    lds[tid] = v;
    __syncthreads();
    int t = v;
    for (int off = 1; off < 64; off <<= 1) {
        int add = (tid >= off) ? lds[tid - off] : 0;
        __syncthreads();
        t += add;
        lds[tid] = t;
        __syncthreads();
    }
    if (tid < nc) chunkOff[tid] = t - v;
}

// finalize offs; also produce dinv, btail (mutable), bstart (const)
__global__ void k_scanC(int* __restrict__ offs, const int* __restrict__ chunkOff,
                        const int* __restrict__ cnt, float* __restrict__ dinv,
                        int* __restrict__ btail, int* __restrict__ bstart) {
    int i = blockIdx.x * 256 + threadIdx.x;
    if (i < N_NODES) {
        int v = offs[i] + chunkOff[i >> 10];
        offs[i] = v;
        dinv[i] = 1.f / sqrtf((float)(cnt[i] + 1)); // +1 self-loop
        if ((i & 255) == 0) { btail[i >> 8] = v; bstart[i >> 8] = v; }
        if (i == 0) bstart[NBUCK] = N_EDGES;
    }
}

// Pass A: bucket edges by dst>>8 into bucket-major ebuf (packed src|((dst&255)<<16))
__global__ __launch_bounds__(256) void k_bucket(
    const int* __restrict__ esrc, const int* __restrict__ edst,
    int* __restrict__ btail, int* __restrict__ ebuf) {
    __shared__ int hcnt[NBUCK];
    __shared__ int hbase[NBUCK];
    int t = threadIdx.x;
    for (int i = t; i < NBUCK; i += 256) hcnt[i] = 0;
    __syncthreads();
    int e0 = blockIdx.x * 2048 + t;
    int d[8], s[8];
#pragma unroll
    for (int i = 0; i < 8; ++i) {
        int e = e0 + i * 256;
        if (e < N_EDGES) {
            d[i] = edst[e];
            s[i] = esrc[e];
            atomicAdd(&hcnt[d[i] >> 8], 1);
        } else {
            d[i] = -1;
        }
    }
    __syncthreads();
    for (int i = t; i < NBUCK; i += 256) {
        int c = hcnt[i];
        hbase[i] = (c > 0) ? atomicAdd(&btail[i], c) : 0;
        hcnt[i] = 0;
    }
    __syncthreads();
#pragma unroll
    for (int i = 0; i < 8; ++i) {
        if (d[i] >= 0) {
            int b = d[i] >> 8;
            int p = atomicAdd(&hcnt[b], 1);
            ebuf[hbase[b] + p] = (s[i] & 0xffff) | ((d[i] & 255) << 16);
        }
    }
}

// Pass B: one block per bucket; LDS per-dst counters; writes confined to the
// bucket's CSR window. Entry = src | (bf16(dinv[src]*dinv[dst]) << 16).
__global__ __launch_bounds__(256) void k_fillB(
    const int* __restrict__ ebuf, const int* __restrict__ bstart,
    const int* __restrict__ offs, const float* __restrict__ dinv,
    unsigned int* __restrict__ csrs) {
    __shared__ int loffs[256];
    __shared__ int lcnt[256];
    __shared__ float ldinv[256];
    int b = blockIdx.x, t = threadIdx.x;
    int nbase = b << 8;
    if (nbase + t < N_NODES) {
        loffs[t] = offs[nbase + t];
        ldinv[t] = dinv[nbase + t];
    }
    lcnt[t] = 0;
    __syncthreads();
    int s0 = bstart[b], s1 = bstart[b + 1];
    for (int i = s0 + t; i < s1; i += 256) {
        int pk = ebuf[i];
        int ld = (pk >> 16) & 255;
        int src = pk & 0xffff;
        float w = dinv[src] * ldinv[ld];
        int p = atomicAdd(&lcnt[ld], 1);
        csrs[loffs[ld] + p] = (unsigned)src | ((unsigned)f2b(w) << 16);
    }
}

// ---------------- prep: Wpack (blocks 0..319) + T = relu(id_emb)@Wn_bot (320..447)

__global__ __launch_bounds__(256) void k_prep(
    const float* __restrict__ Wn, const float* __restrict__ convW,
    unsigned short* __restrict__ Wpack,
    const float* __restrict__ id_emb, float* __restrict__ T) {
    int blk = blockIdx.x;
    if (blk < 320) {
        int tid = blk * 256 + threadIdx.x;
        int m = tid >> 14;
        int rem = tid & 16383;
        int ct = rem >> 11, kc = (rem >> 9) & 3, l = (rem >> 3) & 63, j = rem & 7;
        int k = kc * 32 + ((l >> 4) * 8) + j;
        int n = ct * 16 + (l & 15);
        const float* src = (m == 0) ? Wn : (convW + (size_t)(m - 1) * 16384);
        Wpack[tid] = f2b(src[k * 128 + n]);
    } else {
        int t = threadIdx.x;
        int d = t & 127;
        int r = (blk - 320) * 2 + (t >> 7);
        float acc = 0.f;
        for (int k = 0; k < 128; ++k)
            acc = fmaf(fmaxf(id_emb[r * 128 + k], 0.f), Wn[(128 + k) * 128 + d], acc);
        T[r * 128 + d] = acc;
    }
}

// ---------------- MFMA encoder + fused segmax (layer 0) ----------------

__global__ __launch_bounds__(256) void k_encoder(
    const float* __restrict__ pos, const int* __restrict__ idfeat,
    const float* __restrict__ Wp, const float* __restrict__ bp,
    const unsigned short* __restrict__ WpackE, const float* __restrict__ bn,
    const float* __restrict__ T, unsigned short* __restrict__ A16,
    const int* __restrict__ batch, float* __restrict__ gbuf) {
    __shared__ unsigned short feat[64 * 128]; // 16KB, swizzled; reused as smx
    __shared__ float posl[192];
    __shared__ int bbat[64];
    int t = threadIdx.x;
    int base = blockIdx.x * 64;
    int avail = N_NODES - base;
    if (t < 192) {
        int idx = base * 3 + t;
        posl[t] = (idx < N_NODES * 3) ? pos[idx] : 0.f;
    }
    if (t < 64) bbat[t] = (base + t < N_NODES) ? batch[base + t] : -1;
    __syncthreads();
#pragma unroll
    for (int i = 0; i < 4; ++i) {
        int gid = t + i * 256;
        int row = gid >> 4, kg = gid & 15;
        unsigned short u[8];
        if (row < avail) {
            float p0 = posl[row * 3], p1 = posl[row * 3 + 1], p2 = posl[row * 3 + 2];
#pragma unroll
            for (int j = 0; j < 8; ++j) {
                int d = kg * 8 + j;
                float v = fmaf(p0, Wp[d], fmaf(p1, Wp[128 + d], fmaf(p2, Wp[256 + d], bp[d])));
                u[j] = f2b(fmaxf(v, 0.f));
            }
        } else {
#pragma unroll
            for (int j = 0; j < 8; ++j) u[j] = 0;
        }
        char* dst = (char*)feat + row * 256 + ((kg * 16) ^ ((row & 7) << 4));
        *(uint4*)dst = *(uint4*)u;
    }
    __syncthreads();
    int wid = t >> 6, l = t & 63;
    int r0 = wid * 16;
    f32x4 acc[8];
#pragma unroll
    for (int ct = 0; ct < 8; ++ct) acc[ct] = (f32x4){0.f, 0.f, 0.f, 0.f};
    const bf16x8* wp = (const bf16x8*)WpackE;
#pragma unroll
    for (int kc = 0; kc < 4; ++kc) {
        int row = r0 + (l & 15);
        const char* ap = (const char*)feat + row * 256 +
                         ((kc * 64 + ((l >> 4) * 16)) ^ ((row & 7) << 4));
        bf16x8 afrag = *(const bf16x8*)ap;
#pragma unroll
        for (int ct = 0; ct < 8; ++ct) {
            bf16x8 bfrag = wp[(ct * 4 + kc) * 64 + l];
            acc[ct] = __builtin_amdgcn_mfma_f32_16x16x32_bf16(afrag, bfrag, acc[ct], 0, 0, 0);
        }
    }
    int subrow = (l >> 4) * 4, col0 = l & 15;
    int ids[4];
#pragma unroll
    for (int i = 0; i < 4; ++i) {
        int node = base + r0 + subrow + i;
        ids[i] = (node < N_NODES) ? idfeat[node] : 0;
    }
    __syncthreads(); // all MFMA feat reads done; reuse feat as bf16 smx
#pragma unroll
    for (int ct = 0; ct < 8; ++ct) {
        int col = ct * 16 + col0;
        float bcol = bn[col];
#pragma unroll
        for (int i = 0; i < 4; ++i) {
            int node = base + r0 + subrow + i;
            unsigned short ob = 0;
            if (node < N_NODES) {
                float v = acc[ct][i] + bcol + T[ids[i] * 128 + col];
                ob = f2b(fmaxf(v, 0.f));
                A16[(size_t)node * 128 + col] = ob;
            }
            feat[(r0 + subrow + i) * 128 + col] = ob;
        }
    }
    __syncthreads();
    if (t < 128) {
        int j = 0;
        while (j < 64) {
            int g = bbat[j];
            float m = b2f(feat[j * 128 + t]);
            int k = j + 1;
            while (k < 64 && bbat[k] == g) { m = fmaxf(m, b2f(feat[k * 128 + t])); ++k; }
            if (g >= 0) atomicMax((int*)&gbuf[g * GDIM + t], __float_as_int(m));
            j = k;
        }
    }
}

// ---------------- fused GCN layer: aggregate(h) -> @W -> +b -> relu -> segmax ----
// CSR entry packs src (16b) + bf16 weight (16b): no dependent dinv gather, and
// w = uint_as_float(pk & 0xffff0000) is a single AND.

__global__ __launch_bounds__(512) void k_layer(
    const unsigned short* __restrict__ Hin, unsigned short* __restrict__ Hout,
    const unsigned short* __restrict__ WpackL,
    const int* __restrict__ offs, const int* __restrict__ cnt,
    const unsigned int* __restrict__ csrs, const float* __restrict__ dinv,
    const float* __restrict__ bias, const int* __restrict__ batch,
    float* __restrict__ gbuf, int goff) {
    __shared__ unsigned short hagg[16 * 128]; // 4KB swizzled bf16
    __shared__ float smx[16][132];            // padded
    __shared__ int bb[16];
    int tid = threadIdx.x;
    int wave = tid >> 6, lane = tid & 63;
    int sub = lane >> 5, l = lane & 31;
    int row = wave * 2 + sub;                 // 0..15
    int nbase = blockIdx.x * 16;              // 50000 % 16 == 0
    int node = nbase + row;
    if (tid < 16) bb[tid] = batch[nbase + tid];

    // ---- phase 1: aggregate in h-space (fp32 acc over bf16 msgs)
    int start = offs[node];
    int c = cnt[node];
    float di = dinv[node];
    float sw = di * di;
    const ushort4* B4 = (const ushort4*)Hin;
    ushort4 sv = B4[(size_t)node * 32 + l];
    float4 acc;
    acc.x = sw * b2f(sv.x);
    acc.y = sw * b2f(sv.y);
    acc.z = sw * b2f(sv.z);
    acc.w = sw * b2f(sv.w);
    int j = 0;
    for (; j + 8 <= c; j += 8) {
        unsigned pk[8];
        ushort4 v[8];
#pragma unroll
        for (int i = 0; i < 8; ++i) pk[i] = csrs[start + j + i];
#pragma unroll
        for (int i = 0; i < 8; ++i) v[i] = B4[(size_t)(pk[i] & 0xffffu) * 32 + l];
#pragma unroll
        for (int i = 0; i < 8; ++i) {
            float w = __uint_as_float(pk[i] & 0xffff0000u);
            acc.x = fmaf(w, b2f(v[i].x), acc.x);
            acc.y = fmaf(w, b2f(v[i].y), acc.y);
            acc.z = fmaf(w, b2f(v[i].z), acc.z);
            acc.w = fmaf(w, b2f(v[i].w), acc.w);
        }
    }
    for (; j < c; ++j) {
        unsigned pk = csrs[start + j];
        float w = __uint_as_float(pk & 0xffff0000u);
        ushort4 v = B4[(size_t)(pk & 0xffffu) * 32 + l];
        acc.x = fmaf(w, b2f(v.x), acc.x);
        acc.y = fmaf(w, b2f(v.y), acc.y);
        acc.z = fmaf(w, b2f(v.z), acc.z);
        acc.w = fmaf(w, b2f(v.w), acc.w);
    }
    {
        unsigned short u[4] = {f2b(acc.x), f2b(acc.y), f2b(acc.z), f2b(acc.w)};
        char* dst = (char*)hagg + row * 256 + ((((l >> 1) * 16) ^ ((row & 7) << 4)) + (l & 1) * 8);
        *(uint2*)dst = *(uint2*)u;
    }
    __syncthreads();

    // ---- phase 2: MFMA 16x128 @ 128x128, wave -> col tile
    f32x4 oacc = (f32x4){0.f, 0.f, 0.f, 0.f};
    const bf16x8* wp = (const bf16x8*)WpackL;
#pragma unroll
    for (int kc = 0; kc < 4; ++kc) {
        int arow = lane & 15;
        const char* ap = (const char*)hagg + arow * 256 +
                         ((kc * 64 + ((lane >> 4) * 16)) ^ ((arow & 7) << 4));
        bf16x8 afrag = *(const bf16x8*)ap;
        bf16x8 bfrag = wp[(wave * 4 + kc) * 64 + lane];
        oacc = __builtin_amdgcn_mfma_f32_16x16x32_bf16(afrag, bfrag, oacc, 0, 0, 0);
    }

    // ---- phase 3: bias + relu + store + fused segmax
    int col = wave * 16 + (lane & 15);
    int subrow = (lane >> 4) * 4;
    float bcol = bias[col];
#pragma unroll
    for (int i = 0; i < 4; ++i) {
        int r = subrow + i;
        float v = fmaxf(oacc[i] + bcol, 0.f);
        smx[r][col] = v;
        Hout[(size_t)(nbase + r) * 128 + col] = f2b(v);
    }
    __syncthreads();
    if (tid < 128) {
        int jj = 0;
        while (jj < 16) {
            int g = bb[jj];
            float m = smx[jj][tid];
            int k = jj + 1;
            while (k < 16 && bb[k] == g) { m = fmaxf(m, smx[k][tid]); ++k; }
            atomicMax((int*)&gbuf[g * GDIM + goff + tid], __float_as_int(m));
            jj = k;
        }
    }
}

// ---------------- final: out[G,128] = gbuf[G,640] @ Wa[640,128] + ba

__global__ __launch_bounds__(128) void k_final(const float* __restrict__ gbuf,
                                               const float* __restrict__ Wa,
                                               const float* __restrict__ ba,
                                               float* __restrict__ out) {
    __shared__ float gr[GDIM];
    int g = blockIdx.x, t = threadIdx.x;
    for (int i = t; i < GDIM; i += 128) gr[i] = gbuf[g * GDIM + i];
    __syncthreads();
    float acc = ba[t];
    for (int k = 0; k < GDIM; ++k) acc = fmaf(gr[k], Wa[k * 128 + t], acc);
    out[g * 128 + t] = acc;
}

// ---------------- launch ----------------

extern "C" void kernel_launch(void* const* d_in, const int* in_sizes, int n_in,
                              void* d_out, int out_size, void* d_ws, size_t ws_size,
                              hipStream_t stream) {
    const float* pos    = (const float*)d_in[0];
    const int*   idfeat = (const int*)d_in[1];
    const int*   eidx   = (const int*)d_in[2];
    const int*   batch  = (const int*)d_in[3];
    const float* Wp     = (const float*)d_in[5];
    const float* bp     = (const float*)d_in[6];
    const float* id_emb = (const float*)d_in[7];
    const float* Wn     = (const float*)d_in[8];
    const float* bn     = (const float*)d_in[9];
    const float* convW  = (const float*)d_in[10];
    const float* convb  = (const float*)d_in[11];
    const float* Wa     = (const float*)d_in[12];
    const float* ba     = (const float*)d_in[13];
    float* out = (float*)d_out;

    const int* esrc = eidx;
    const int* edst = eidx + N_EDGES;

    char* w = (char*)d_ws;
    auto alloc = [&](size_t bytes) -> char* {
        char* p = w;
        w += (bytes + 255) & ~(size_t)255;
        return p;
    };
    // cnt and gbuf adjacent -> single memset clears both
    int*   cnt  = (int*)alloc((size_t)N_NODES * 4);
    float* gbuf = (float*)alloc((size_t)NGRAPH * GDIM * 4);
    size_t zbytes = (((size_t)N_NODES * 4 + 255) & ~(size_t)255) + (size_t)NGRAPH * GDIM * 4;
    unsigned short* A16a = (unsigned short*)alloc((size_t)N_NODES * D * 2);
    unsigned short* A16b = (unsigned short*)alloc((size_t)N_NODES * D * 2);
    float* dinv = (float*)alloc((size_t)N_NODES * 4);
    int*   offs = (int*)alloc((size_t)(N_NODES + 1) * 4);
    int*   csum = (int*)alloc(64 * 4);
    int*   coff = (int*)alloc(64 * 4);
    unsigned int* csrs = (unsigned int*)alloc((size_t)N_EDGES * 4);
    int*   ebuf = (int*)alloc((size_t)N_EDGES * 4);
    int*   btail= (int*)alloc((NBUCK + 1) * 4);
    int*   bstart=(int*)alloc((NBUCK + 1) * 4);
    float* T    = (float*)alloc((size_t)256 * D * 4);
    unsigned short* Wpack = (unsigned short*)alloc((size_t)5 * 16384 * 2);

    hipMemsetAsync(cnt, 0, zbytes, stream);

    k_count<<<(N_EDGES + 255) / 256, 256, 0, stream>>>(edst, cnt);

    int nchunk = (N_NODES + 1023) / 1024; // 49
    k_scanA<<<nchunk, 256, 0, stream>>>(cnt, offs, csum);
    k_scanB<<<1, 64, 0, stream>>>(csum, coff, nchunk);
    k_scanC<<<(N_NODES + 255) / 256, 256, 0, stream>>>(offs, coff, cnt, dinv, btail, bstart);

    k_bucket<<<(N_EDGES + 2047) / 2048, 256, 0, stream>>>(esrc, edst, btail, ebuf);
    k_fillB<<<NBUCK, 256, 0, stream>>>(ebuf, bstart, offs, dinv, csrs);

    k_prep<<<448, 256, 0, stream>>>(Wn, convW, Wpack, id_emb, T);
    k_encoder<<<(N_NODES + 63) / 64, 256, 0, stream>>>(pos, idfeat, Wp, bp, Wpack, bn, T,
                                                       A16a, batch, gbuf);

    unsigned short* Hin = A16a;
    unsigned short* Hout = A16b;
    for (int l = 0; l < NLAYER; ++l) {
        k_layer<<<N_NODES / 16, 512, 0, stream>>>(Hin, Hout, Wpack + (size_t)(l + 1) * 16384,
                                                  offs, cnt, csrs, dinv,
                                                  convb + (size_t)l * D, batch, gbuf,
                                                  (l + 1) * D);
        unsigned short* tmp = Hin; Hin = Hout; Hout = tmp;
    }

    k_final<<<NGRAPH, 128, 0, stream>>>(gbuf, Wa, ba, out);
}

// Round 11
// 288.712 us; speedup vs baseline: 1.0354x; 1.0354x over previous
//
#include <hip/hip_runtime.h>

#define N_NODES 50000
#define N_EDGES 800000
#define D 128
#define NLAYER 4
#define NGRAPH 128
#define GDIM (5 * D) // 640
#define NBUCK 196    // dst>>8 buckets
#define BCAP 4608    // fixed bucket capacity (mean 4096, sigma 64 -> +8 sigma)

typedef __attribute__((ext_vector_type(8))) short bf16x8;
typedef __attribute__((ext_vector_type(4))) float f32x4;

__device__ __forceinline__ float b2f(unsigned short u) {
    return __uint_as_float(((unsigned)u) << 16);
}
__device__ __forceinline__ unsigned short f2b(float f) {
    unsigned u = __float_as_uint(f);
    unsigned r = (u + 0x7fffu + ((u >> 16) & 1u)) >> 16; // round-to-nearest-even
    return (unsigned short)r;
}

// ---- Pass A: count dst degrees AND bucket edges by dst>>8 into fixed-capacity
// bucket-major ebuf (packed src | ((dst&255)<<16)). bcnt_rel pre-zeroed.

__global__ __launch_bounds__(256) void k_bucket(
    const int* __restrict__ esrc, const int* __restrict__ edst,
    int* __restrict__ cnt, int* __restrict__ bcnt_rel, int* __restrict__ ebuf) {
    __shared__ int hcnt[NBUCK];
    __shared__ int hbase[NBUCK];
    int t = threadIdx.x;
    for (int i = t; i < NBUCK; i += 256) hcnt[i] = 0;
    __syncthreads();
    int e0 = blockIdx.x * 2048 + t;
    int d[8], s[8];
#pragma unroll
    for (int i = 0; i < 8; ++i) {
        int e = e0 + i * 256;
        if (e < N_EDGES) {
            d[i] = edst[e];
            s[i] = esrc[e];
            atomicAdd(&cnt[d[i]], 1);
            atomicAdd(&hcnt[d[i] >> 8], 1);
        } else {
            d[i] = -1;
        }
    }
    __syncthreads();
    for (int i = t; i < NBUCK; i += 256) {
        int c = hcnt[i];
        hbase[i] = (c > 0) ? (i * BCAP + atomicAdd(&bcnt_rel[i], c)) : 0;
        hcnt[i] = 0;
    }
    __syncthreads();
#pragma unroll
    for (int i = 0; i < 8; ++i) {
        if (d[i] >= 0) {
            int b = d[i] >> 8;
            int p = atomicAdd(&hcnt[b], 1);
            int pos = hbase[b] + p;
            if (pos < (b + 1) * BCAP) // overflow guard (never triggers for this input)
                ebuf[pos] = (s[i] & 0xffff) | ((d[i] & 255) << 16);
        }
    }
}

// ---- scans over cnt -> offs (exclusive prefix) ----

__global__ void k_scanA(const int* __restrict__ cnt, int* __restrict__ offs,
                        int* __restrict__ chunkSum) {
    __shared__ int lds[256];
    int tid = threadIdx.x;
    int base = blockIdx.x * 1024 + tid * 4;
    int v[4];
    int s = 0;
#pragma unroll
    for (int j = 0; j < 4; ++j) {
        int idx = base + j;
        v[j] = (idx < N_NODES) ? cnt[idx] : 0;
        s += v[j];
    }
    lds[tid] = s;
    __syncthreads();
    int t = s;
    for (int off = 1; off < 256; off <<= 1) {
        int add = (tid >= off) ? lds[tid - off] : 0;
        __syncthreads();
        t += add;
        lds[tid] = t;
        __syncthreads();
    }
    int run = t - s;
#pragma unroll
    for (int j = 0; j < 4; ++j) {
        int idx = base + j;
        if (idx < N_NODES) offs[idx] = run;
        run += v[j];
    }
    if (tid == 255) chunkSum[blockIdx.x] = t;
}

__global__ void k_scanB(const int* __restrict__ chunkSum, int* __restrict__ chunkOff,
                        int nc) {
    __shared__ int lds[64];
    int tid = threadIdx.x;
    int v = (tid < nc) ? chunkSum[tid] : 0;
    lds[tid] = v;
    __syncthreads();
    int t = v;
    for (int off = 1; off < 64; off <<= 1) {
        int add = (tid >= off) ? lds[tid - off] : 0;
        __syncthreads();
        t += add;
        lds[tid] = t;
        __syncthreads();
    }
    if (tid < nc) chunkOff[tid] = t - v;
}

// finalize offs; produce dinv; histogram (batch,deg) keys for node sort
__global__ void k_scanC(int* __restrict__ offs, const int* __restrict__ chunkOff,
                        const int* __restrict__ cnt, float* __restrict__ dinv,
                        const int* __restrict__ batch, int* __restrict__ hist2) {
    int i = blockIdx.x * 256 + threadIdx.x;
    if (i < N_NODES) {
        offs[i] += chunkOff[i >> 10];
        int c = cnt[i];
        dinv[i] = 1.f / sqrtf((float)(c + 1)); // +1 self-loop
        atomicAdd(&hist2[batch[i] * 128 + min(c, 127)], 1);
    }
}

// in-place exclusive scan of 16384 bins (1 block, 1024 threads x 16)
__global__ __launch_bounds__(1024) void k_scan16k(int* __restrict__ hist2) {
    __shared__ int lds[1024];
    int t = threadIdx.x;
    int v[16];
    int s = 0;
#pragma unroll
    for (int j = 0; j < 16; ++j) { v[j] = hist2[t * 16 + j]; s += v[j]; }
    lds[t] = s;
    __syncthreads();
    int tot = s;
    for (int off = 1; off < 1024; off <<= 1) {
        int add = (t >= off) ? lds[t - off] : 0;
        __syncthreads();
        tot += add;
        lds[t] = tot;
        __syncthreads();
    }
    int run = tot - s;
#pragma unroll
    for (int j = 0; j < 16; ++j) { hist2[t * 16 + j] = run; run += v[j]; }
}

// scatter node ids into (batch, degree)-sorted perm (hist2 used as running heads)
__global__ void k_scatter(const int* __restrict__ cnt, const int* __restrict__ batch,
                          int* __restrict__ hist2, int* __restrict__ perm) {
    int i = blockIdx.x * 256 + threadIdx.x;
    if (i < N_NODES) {
        int key = batch[i] * 128 + min(cnt[i], 127);
        int p = atomicAdd(&hist2[key], 1);
        perm[p] = i;
    }
}

// ---- Pass B: one block per bucket; LDS per-dst counters; writes confined to the
// bucket's CSR window. Entry = src | (bf16(dinv[src]*dinv[dst]) << 16).
__global__ __launch_bounds__(256) void k_fillB(
    const int* __restrict__ ebuf, const int* __restrict__ bcnt_rel,
    const int* __restrict__ offs, const float* __restrict__ dinv,
    unsigned int* __restrict__ csrs) {
    __shared__ int loffs[256];
    __shared__ int lcnt[256];
    __shared__ float ldinv[256];
    int b = blockIdx.x, t = threadIdx.x;
    int nbase = b << 8;
    if (nbase + t < N_NODES) {
        loffs[t] = offs[nbase + t];
        ldinv[t] = dinv[nbase + t];
    }
    lcnt[t] = 0;
    __syncthreads();
    int s0 = b * BCAP, s1 = b * BCAP + bcnt_rel[b];
    for (int i = s0 + t; i < s1; i += 256) {
        int pk = ebuf[i];
        int ld = (pk >> 16) & 255;
        int src = pk & 0xffff;
        float w = dinv[src] * ldinv[ld];
        int p = atomicAdd(&lcnt[ld], 1);
        csrs[loffs[ld] + p] = (unsigned)src | ((unsigned)f2b(w) << 16);
    }
}

// ---- prep: Wpack (blocks 0..319) + T = relu(id_emb)@Wn_bot (320..447)

__global__ __launch_bounds__(256) void k_prep(
    const float* __restrict__ Wn, const float* __restrict__ convW,
    unsigned short* __restrict__ Wpack,
    const float* __restrict__ id_emb, float* __restrict__ T) {
    int blk = blockIdx.x;
    if (blk < 320) {
        int tid = blk * 256 + threadIdx.x;
        int m = tid >> 14;
        int rem = tid & 16383;
        int ct = rem >> 11, kc = (rem >> 9) & 3, l = (rem >> 3) & 63, j = rem & 7;
        int k = kc * 32 + ((l >> 4) * 8) + j;
        int n = ct * 16 + (l & 15);
        const float* src = (m == 0) ? Wn : (convW + (size_t)(m - 1) * 16384);
        Wpack[tid] = f2b(src[k * 128 + n]);
    } else {
        int t = threadIdx.x;
        int d = t & 127;
        int r = (blk - 320) * 2 + (t >> 7);
        float acc = 0.f;
        for (int k = 0; k < 128; ++k)
            acc = fmaf(fmaxf(id_emb[r * 128 + k], 0.f), Wn[(128 + k) * 128 + d], acc);
        T[r * 128 + d] = acc;
    }
}

// ---- MFMA encoder + fused segmax (layer 0, original node order) ----

__global__ __launch_bounds__(256) void k_encoder(
    const float* __restrict__ pos, const int* __restrict__ idfeat,
    const float* __restrict__ Wp, const float* __restrict__ bp,
    const unsigned short* __restrict__ WpackE, const float* __restrict__ bn,
    const float* __restrict__ T, unsigned short* __restrict__ A16,
    const int* __restrict__ batch, float* __restrict__ gbuf) {
    __shared__ unsigned short feat[64 * 128]; // 16KB, swizzled; reused as smx
    __shared__ float posl[192];
    __shared__ int bbat[64];
    int t = threadIdx.x;
    int base = blockIdx.x * 64;
    int avail = N_NODES - base;
    if (t < 192) {
        int idx = base * 3 + t;
        posl[t] = (idx < N_NODES * 3) ? pos[idx] : 0.f;
    }
    if (t < 64) bbat[t] = (base + t < N_NODES) ? batch[base + t] : -1;
    __syncthreads();
#pragma unroll
    for (int i = 0; i < 4; ++i) {
        int gid = t + i * 256;
        int row = gid >> 4, kg = gid & 15;
        unsigned short u[8];
        if (row < avail) {
            float p0 = posl[row * 3], p1 = posl[row * 3 + 1], p2 = posl[row * 3 + 2];
#pragma unroll
            for (int j = 0; j < 8; ++j) {
                int d = kg * 8 + j;
                float v = fmaf(p0, Wp[d], fmaf(p1, Wp[128 + d], fmaf(p2, Wp[256 + d], bp[d])));
                u[j] = f2b(fmaxf(v, 0.f));
            }
        } else {
#pragma unroll
            for (int j = 0; j < 8; ++j) u[j] = 0;
        }
        char* dst = (char*)feat + row * 256 + ((kg * 16) ^ ((row & 7) << 4));
        *(uint4*)dst = *(uint4*)u;
    }
    __syncthreads();
    int wid = t >> 6, l = t & 63;
    int r0 = wid * 16;
    f32x4 acc[8];
#pragma unroll
    for (int ct = 0; ct < 8; ++ct) acc[ct] = (f32x4){0.f, 0.f, 0.f, 0.f};
    const bf16x8* wp = (const bf16x8*)WpackE;
#pragma unroll
    for (int kc = 0; kc < 4; ++kc) {
        int row = r0 + (l & 15);
        const char* ap = (const char*)feat + row * 256 +
                         ((kc * 64 + ((l >> 4) * 16)) ^ ((row & 7) << 4));
        bf16x8 afrag = *(const bf16x8*)ap;
#pragma unroll
        for (int ct = 0; ct < 8; ++ct) {
            bf16x8 bfrag = wp[(ct * 4 + kc) * 64 + l];
            acc[ct] = __builtin_amdgcn_mfma_f32_16x16x32_bf16(afrag, bfrag, acc[ct], 0, 0, 0);
        }
    }
    int subrow = (l >> 4) * 4, col0 = l & 15;
    int ids[4];
#pragma unroll
    for (int i = 0; i < 4; ++i) {
        int node = base + r0 + subrow + i;
        ids[i] = (node < N_NODES) ? idfeat[node] : 0;
    }
    __syncthreads(); // all MFMA feat reads done; reuse feat as bf16 smx
#pragma unroll
    for (int ct = 0; ct < 8; ++ct) {
        int col = ct * 16 + col0;
        float bcol = bn[col];
#pragma unroll
        for (int i = 0; i < 4; ++i) {
            int node = base + r0 + subrow + i;
            unsigned short ob = 0;
            if (node < N_NODES) {
                float v = acc[ct][i] + bcol + T[ids[i] * 128 + col];
                ob = f2b(fmaxf(v, 0.f));
                A16[(size_t)node * 128 + col] = ob;
            }
            feat[(r0 + subrow + i) * 128 + col] = ob;
        }
    }
    __syncthreads();
    if (t < 128) {
        int j = 0;
        while (j < 64) {
            int g = bbat[j];
            float m = b2f(feat[j * 128 + t]);
            int k = j + 1;
            while (k < 64 && bbat[k] == g) { m = fmaxf(m, b2f(feat[k * 128 + t])); ++k; }
            if (g >= 0) atomicMax((int*)&gbuf[g * GDIM + t], __float_as_int(m));
            j = k;
        }
    }
}

// ---- fused GCN layer over (batch,degree)-sorted nodes ----
// Waves within a block get near-equal degrees -> no straggler gating.

__global__ __launch_bounds__(512) void k_layer(
    const unsigned short* __restrict__ Hin, unsigned short* __restrict__ Hout,
    const unsigned short* __restrict__ WpackL,
    const int* __restrict__ offs, const int* __restrict__ cnt,
    const unsigned int* __restrict__ csrs, const float* __restrict__ dinv,
    const float* __restrict__ bias, const int* __restrict__ batch,
    const int* __restrict__ perm, float* __restrict__ gbuf, int goff) {
    __shared__ unsigned short hagg[16 * 128]; // 4KB swizzled bf16
    __shared__ float smx[16][132];            // padded
    __shared__ int bb[16];
    __shared__ int snode[16];
    int tid = threadIdx.x;
    int wave = tid >> 6, lane = tid & 63;
    int sub = lane >> 5, l = lane & 31;
    int row = wave * 2 + sub;                 // 0..15
    int nbase = blockIdx.x * 16;              // 50000 % 16 == 0
    if (tid < 16) {
        int n = perm[nbase + tid];
        snode[tid] = n;
        bb[tid] = batch[n];
    }
    int node = perm[nbase + row];

    // ---- phase 1: aggregate in h-space (fp32 acc over bf16 msgs)
    int start = offs[node];
    int c = cnt[node];
    float di = dinv[node];
    float sw = di * di;
    const ushort4* B4 = (const ushort4*)Hin;
    ushort4 sv = B4[(size_t)node * 32 + l];
    float4 acc;
    acc.x = sw * b2f(sv.x);
    acc.y = sw * b2f(sv.y);
    acc.z = sw * b2f(sv.z);
    acc.w = sw * b2f(sv.w);
    int j = 0;
    for (; j + 8 <= c; j += 8) {
        unsigned pk[8];
        ushort4 v[8];
#pragma unroll
        for (int i = 0; i < 8; ++i) pk[i] = csrs[start + j + i];
#pragma unroll
        for (int i = 0; i < 8; ++i) v[i] = B4[(size_t)(pk[i] & 0xffffu) * 32 + l];
#pragma unroll
        for (int i = 0; i < 8; ++i) {
            float w = __uint_as_float(pk[i] & 0xffff0000u);
            acc.x = fmaf(w, b2f(v[i].x), acc.x);
            acc.y = fmaf(w, b2f(v[i].y), acc.y);
            acc.z = fmaf(w, b2f(v[i].z), acc.z);
            acc.w = fmaf(w, b2f(v[i].w), acc.w);
        }
    }
    for (; j < c; ++j) {
        unsigned pk = csrs[start + j];
        float w = __uint_as_float(pk & 0xffff0000u);
        ushort4 v = B4[(size_t)(pk & 0xffffu) * 32 + l];
        acc.x = fmaf(w, b2f(v.x), acc.x);
        acc.y = fmaf(w, b2f(v.y), acc.y);
        acc.z = fmaf(w, b2f(v.z), acc.z);
        acc.w = fmaf(w, b2f(v.w), acc.w);
    }
    {
        unsigned short u[4] = {f2b(acc.x), f2b(acc.y), f2b(acc.z), f2b(acc.w)};
        char* dst = (char*)hagg + row * 256 + ((((l >> 1) * 16) ^ ((row & 7) << 4)) + (l & 1) * 8);
        *(uint2*)dst = *(uint2*)u;
    }
    __syncthreads();

    // ---- phase 2: MFMA 16x128 @ 128x128, wave -> col tile
    f32x4 oacc = (f32x4){0.f, 0.f, 0.f, 0.f};
    const bf16x8* wp = (const bf16x8*)WpackL;
#pragma unroll
    for (int kc = 0; kc < 4; ++kc) {
        int arow = lane & 15;
        const char* ap = (const char*)hagg + arow * 256 +
                         ((kc * 64 + ((lane >> 4) * 16)) ^ ((arow & 7) << 4));
        bf16x8 afrag = *(const bf16x8*)ap;
        bf16x8 bfrag = wp[(wave * 4 + kc) * 64 + lane];
        oacc = __builtin_amdgcn_mfma_f32_16x16x32_bf16(afrag, bfrag, oacc, 0, 0, 0);
    }

    // ---- phase 3: bias + relu + store + fused segmax
    int col = wave * 16 + (lane & 15);
    int subrow = (lane >> 4) * 4;
    float bcol = bias[col];
#pragma unroll
    for (int i = 0; i < 4; ++i) {
        int r = subrow + i;
        float v = fmaxf(oacc[i] + bcol, 0.f);
        smx[r][col] = v;
        Hout[(size_t)snode[r] * 128 + col] = f2b(v);
    }
    __syncthreads();
    if (tid < 128) {
        int jj = 0;
        while (jj < 16) {
            int g = bb[jj];
            float m = smx[jj][tid];
            int k = jj + 1;
            while (k < 16 && bb[k] == g) { m = fmaxf(m, smx[k][tid]); ++k; }
            atomicMax((int*)&gbuf[g * GDIM + goff + tid], __float_as_int(m));
            jj = k;
        }
    }
}

// ---- final: out[G,128] = gbuf[G,640] @ Wa[640,128] + ba

__global__ __launch_bounds__(128) void k_final(const float* __restrict__ gbuf,
                                               const float* __restrict__ Wa,
                                               const float* __restrict__ ba,
                                               float* __restrict__ out) {
    __shared__ float gr[GDIM];
    int g = blockIdx.x, t = threadIdx.x;
    for (int i = t; i < GDIM; i += 128) gr[i] = gbuf[g * GDIM + i];
    __syncthreads();
    float acc = ba[t];
    for (int k = 0; k < GDIM; ++k) acc = fmaf(gr[k], Wa[k * 128 + t], acc);
    out[g * 128 + t] = acc;
}

// ---- launch ----

extern "C" void kernel_launch(void* const* d_in, const int* in_sizes, int n_in,
                              void* d_out, int out_size, void* d_ws, size_t ws_size,
                              hipStream_t stream) {
    const float* pos    = (const float*)d_in[0];
    const int*   idfeat = (const int*)d_in[1];
    const int*   eidx   = (const int*)d_in[2];
    const int*   batch  = (const int*)d_in[3];
    const float* Wp     = (const float*)d_in[5];
    const float* bp     = (const float*)d_in[6];
    const float* id_emb = (const float*)d_in[7];
    const float* Wn     = (const float*)d_in[8];
    const float* bn     = (const float*)d_in[9];
    const float* convW  = (const float*)d_in[10];
    const float* convb  = (const float*)d_in[11];
    const float* Wa     = (const float*)d_in[12];
    const float* ba     = (const float*)d_in[13];
    float* out = (float*)d_out;

    const int* esrc = eidx;
    const int* edst = eidx + N_EDGES;

    char* w = (char*)d_ws;
    auto alloc = [&](size_t bytes) -> char* {
        char* p = w;
        w += (bytes + 255) & ~(size_t)255;
        return p;
    };
    // zero region: cnt + gbuf + hist2 + bcnt_rel (single memset)
    char* zstart = w;
    int*   cnt      = (int*)alloc((size_t)N_NODES * 4);
    float* gbuf     = (float*)alloc((size_t)NGRAPH * GDIM * 4);
    int*   hist2    = (int*)alloc((size_t)16384 * 4);
    int*   bcnt_rel = (int*)alloc((size_t)NBUCK * 4);
    size_t zbytes = (size_t)(w - zstart);

    unsigned short* A16a = (unsigned short*)alloc((size_t)N_NODES * D * 2);
    unsigned short* A16b = (unsigned short*)alloc((size_t)N_NODES * D * 2);
    float* dinv = (float*)alloc((size_t)N_NODES * 4);
    int*   offs = (int*)alloc((size_t)(N_NODES + 1) * 4);
    int*   csum = (int*)alloc(64 * 4);
    int*   coff = (int*)alloc(64 * 4);
    unsigned int* csrs = (unsigned int*)alloc((size_t)N_EDGES * 4);
    int*   ebuf = (int*)alloc((size_t)NBUCK * BCAP * 4);
    int*   perm = (int*)alloc((size_t)N_NODES * 4);
    float* T    = (float*)alloc((size_t)256 * D * 4);
    unsigned short* Wpack = (unsigned short*)alloc((size_t)5 * 16384 * 2);

    hipMemsetAsync(zstart, 0, zbytes, stream);

    k_bucket<<<(N_EDGES + 2047) / 2048, 256, 0, stream>>>(esrc, edst, cnt, bcnt_rel, ebuf);

    int nchunk = (N_NODES + 1023) / 1024; // 49
    k_scanA<<<nchunk, 256, 0, stream>>>(cnt, offs, csum);
    k_scanB<<<1, 64, 0, stream>>>(csum, coff, nchunk);
    k_scanC<<<(N_NODES + 255) / 256, 256, 0, stream>>>(offs, coff, cnt, dinv, batch, hist2);
    k_scan16k<<<1, 1024, 0, stream>>>(hist2);
    k_scatter<<<(N_NODES + 255) / 256, 256, 0, stream>>>(cnt, batch, hist2, perm);

    k_fillB<<<NBUCK, 256, 0, stream>>>(ebuf, bcnt_rel, offs, dinv, csrs);

    k_prep<<<448, 256, 0, stream>>>(Wn, convW, Wpack, id_emb, T);
    k_encoder<<<(N_NODES + 63) / 64, 256, 0, stream>>>(pos, idfeat, Wp, bp, Wpack, bn, T,
                                                       A16a, batch, gbuf);

    unsigned short* Hin = A16a;
    unsigned short* Hout = A16b;
    for (int l = 0; l < NLAYER; ++l) {
        k_layer<<<N_NODES / 16, 512, 0, stream>>>(Hin, Hout, Wpack + (size_t)(l + 1) * 16384,
                                                  offs, cnt, csrs, dinv,
                                                  convb + (size_t)l * D, batch, perm, gbuf,
                                                  (l + 1) * D);
        unsigned short* tmp = Hin; Hin = Hout; Hout = tmp;
    }

    k_final<<<NGRAPH, 128, 0, stream>>>(gbuf, Wa, ba, out);
}

// Round 12
// 281.110 us; speedup vs baseline: 1.0634x; 1.0270x over previous
//
#include <hip/hip_runtime.h>

#define N_NODES 50000
#define N_EDGES 800000
#define D 128
#define NLAYER 4
#define NGRAPH 128
#define GDIM (5 * D) // 640
#define NBUCK 196    // dst>>8 buckets
#define BCAP 4608    // fixed bucket capacity (mean 4096 -> +8 sigma)

typedef __attribute__((ext_vector_type(8))) short bf16x8;
typedef __attribute__((ext_vector_type(4))) float f32x4;

__device__ __forceinline__ float b2f(unsigned short u) {
    return __uint_as_float(((unsigned)u) << 16);
}
__device__ __forceinline__ unsigned short f2b(float f) {
    unsigned u = __float_as_uint(f);
    unsigned r = (u + 0x7fffu + ((u >> 16) & 1u)) >> 16; // round-to-nearest-even
    return (unsigned short)r;
}

// ---- Pass A: count dst degrees AND bucket edges by dst>>8 into fixed-capacity
// bucket-major ebuf (packed src | ((dst&255)<<16)). bcnt_rel pre-zeroed.

__global__ __launch_bounds__(256) void k_bucket(
    const int* __restrict__ esrc, const int* __restrict__ edst,
    int* __restrict__ cnt, int* __restrict__ bcnt_rel, int* __restrict__ ebuf) {
    __shared__ int hcnt[NBUCK];
    __shared__ int hbase[NBUCK];
    int t = threadIdx.x;
    for (int i = t; i < NBUCK; i += 256) hcnt[i] = 0;
    __syncthreads();
    int e0 = blockIdx.x * 2048 + t;
    int d[8], s[8];
#pragma unroll
    for (int i = 0; i < 8; ++i) {
        int e = e0 + i * 256;
        if (e < N_EDGES) {
            d[i] = edst[e];
            s[i] = esrc[e];
            atomicAdd(&cnt[d[i]], 1);
            atomicAdd(&hcnt[d[i] >> 8], 1);
        } else {
            d[i] = -1;
        }
    }
    __syncthreads();
    for (int i = t; i < NBUCK; i += 256) {
        int c = hcnt[i];
        hbase[i] = (c > 0) ? (i * BCAP + atomicAdd(&bcnt_rel[i], c)) : 0;
        hcnt[i] = 0;
    }
    __syncthreads();
#pragma unroll
    for (int i = 0; i < 8; ++i) {
        if (d[i] >= 0) {
            int b = d[i] >> 8;
            int p = atomicAdd(&hcnt[b], 1);
            int pos = hbase[b] + p;
            if (pos < (b + 1) * BCAP)
                ebuf[pos] = (s[i] & 0xffff) | ((d[i] & 255) << 16);
        }
    }
}

// ---- scans over cnt -> offs (exclusive prefix) ----

__global__ void k_scanA(const int* __restrict__ cnt, int* __restrict__ offs,
                        int* __restrict__ chunkSum) {
    __shared__ int lds[256];
    int tid = threadIdx.x;
    int base = blockIdx.x * 1024 + tid * 4;
    int v[4];
    int s = 0;
#pragma unroll
    for (int j = 0; j < 4; ++j) {
        int idx = base + j;
        v[j] = (idx < N_NODES) ? cnt[idx] : 0;
        s += v[j];
    }
    lds[tid] = s;
    __syncthreads();
    int t = s;
    for (int off = 1; off < 256; off <<= 1) {
        int add = (tid >= off) ? lds[tid - off] : 0;
        __syncthreads();
        t += add;
        lds[tid] = t;
        __syncthreads();
    }
    int run = t - s;
#pragma unroll
    for (int j = 0; j < 4; ++j) {
        int idx = base + j;
        if (idx < N_NODES) offs[idx] = run;
        run += v[j];
    }
    if (tid == 255) chunkSum[blockIdx.x] = t;
}

__global__ void k_scanB(const int* __restrict__ chunkSum, int* __restrict__ chunkOff,
                        int nc) {
    __shared__ int lds[64];
    int tid = threadIdx.x;
    int v = (tid < nc) ? chunkSum[tid] : 0;
    lds[tid] = v;
    __syncthreads();
    int t = v;
    for (int off = 1; off < 64; off <<= 1) {
        int add = (tid >= off) ? lds[tid - off] : 0;
        __syncthreads();
        t += add;
        lds[tid] = t;
        __syncthreads();
    }
    if (tid < nc) chunkOff[tid] = t - v;
}

// finalize offs; produce dinv; histogram (batch,deg) keys for node sort
__global__ void k_scanC(int* __restrict__ offs, const int* __restrict__ chunkOff,
                        const int* __restrict__ cnt, float* __restrict__ dinv,
                        const int* __restrict__ batch, int* __restrict__ hist2) {
    int i = blockIdx.x * 256 + threadIdx.x;
    if (i < N_NODES) {
        offs[i] += chunkOff[i >> 10];
        int c = cnt[i];
        dinv[i] = 1.f / sqrtf((float)(c + 1)); // +1 self-loop
        atomicAdd(&hist2[batch[i] * 128 + min(c, 127)], 1);
    }
}

// in-place exclusive scan of 16384 bins (1 block, 1024 threads x 16)
__global__ __launch_bounds__(1024) void k_scan16k(int* __restrict__ hist2) {
    __shared__ int lds[1024];
    int t = threadIdx.x;
    int v[16];
    int s = 0;
#pragma unroll
    for (int j = 0; j < 16; ++j) { v[j] = hist2[t * 16 + j]; s += v[j]; }
    lds[t] = s;
    __syncthreads();
    int tot = s;
    for (int off = 1; off < 1024; off <<= 1) {
        int add = (t >= off) ? lds[t - off] : 0;
        __syncthreads();
        tot += add;
        lds[t] = tot;
        __syncthreads();
    }
    int run = tot - s;
#pragma unroll
    for (int j = 0; j < 16; ++j) { hist2[t * 16 + j] = run; run += v[j]; }
}

// scatter node ids into (batch, degree)-sorted perm
__global__ void k_scatter(const int* __restrict__ cnt, const int* __restrict__ batch,
                          int* __restrict__ hist2, int* __restrict__ perm) {
    int i = blockIdx.x * 256 + threadIdx.x;
    if (i < N_NODES) {
        int key = batch[i] * 128 + min(cnt[i], 127);
        int p = atomicAdd(&hist2[key], 1);
        perm[p] = i;
    }
}

// ---- Pass B: one block per bucket; LDS per-dst counters; CSR entry packs
// src (16b) + bf16 weight dinv[src]*dinv[dst] (16b).
__global__ __launch_bounds__(256) void k_fillB(
    const int* __restrict__ ebuf, const int* __restrict__ bcnt_rel,
    const int* __restrict__ offs, const float* __restrict__ dinv,
    unsigned int* __restrict__ csrs) {
    __shared__ int loffs[256];
    __shared__ int lcnt[256];
    __shared__ float ldinv[256];
    int b = blockIdx.x, t = threadIdx.x;
    int nbase = b << 8;
    if (nbase + t < N_NODES) {
        loffs[t] = offs[nbase + t];
        ldinv[t] = dinv[nbase + t];
    }
    lcnt[t] = 0;
    __syncthreads();
    int s0 = b * BCAP, s1 = b * BCAP + bcnt_rel[b];
    for (int i = s0 + t; i < s1; i += 256) {
        int pk = ebuf[i];
        int ld = (pk >> 16) & 255;
        int src = pk & 0xffff;
        float w = dinv[src] * ldinv[ld];
        int p = atomicAdd(&lcnt[ld], 1);
        csrs[loffs[ld] + p] = (unsigned)src | ((unsigned)f2b(w) << 16);
    }
}

// ---- prep: Wpack (blocks 0..319) + T = relu(id_emb)@Wn_bot (320..447)

__global__ __launch_bounds__(256) void k_prep(
    const float* __restrict__ Wn, const float* __restrict__ convW,
    unsigned short* __restrict__ Wpack,
    const float* __restrict__ id_emb, float* __restrict__ T) {
    int blk = blockIdx.x;
    if (blk < 320) {
        int tid = blk * 256 + threadIdx.x;
        int m = tid >> 14;
        int rem = tid & 16383;
        int ct = rem >> 11, kc = (rem >> 9) & 3, l = (rem >> 3) & 63, j = rem & 7;
        int k = kc * 32 + ((l >> 4) * 8) + j;
        int n = ct * 16 + (l & 15);
        const float* src = (m == 0) ? Wn : (convW + (size_t)(m - 1) * 16384);
        Wpack[tid] = f2b(src[k * 128 + n]);
    } else {
        int t = threadIdx.x;
        int d = t & 127;
        int r = (blk - 320) * 2 + (t >> 7);
        float acc = 0.f;
        for (int k = 0; k < 128; ++k)
            acc = fmaf(fmaxf(id_emb[r * 128 + k], 0.f), Wn[(128 + k) * 128 + d], acc);
        T[r * 128 + d] = acc;
    }
}

// ---- MFMA encoder + fused segmax (layer 0, original node order) ----

__global__ __launch_bounds__(256) void k_encoder(
    const float* __restrict__ pos, const int* __restrict__ idfeat,
    const float* __restrict__ Wp, const float* __restrict__ bp,
    const unsigned short* __restrict__ WpackE, const float* __restrict__ bn,
    const float* __restrict__ T, unsigned short* __restrict__ A16,
    const int* __restrict__ batch, float* __restrict__ gbuf) {
    __shared__ unsigned short feat[64 * 128]; // 16KB, swizzled; reused as smx
    __shared__ float posl[192];
    __shared__ int bbat[64];
    int t = threadIdx.x;
    int base = blockIdx.x * 64;
    int avail = N_NODES - base;
    if (t < 192) {
        int idx = base * 3 + t;
        posl[t] = (idx < N_NODES * 3) ? pos[idx] : 0.f;
    }
    if (t < 64) bbat[t] = (base + t < N_NODES) ? batch[base + t] : -1;
    __syncthreads();
#pragma unroll
    for (int i = 0; i < 4; ++i) {
        int gid = t + i * 256;
        int row = gid >> 4, kg = gid & 15;
        unsigned short u[8];
        if (row < avail) {
            float p0 = posl[row * 3], p1 = posl[row * 3 + 1], p2 = posl[row * 3 + 2];
#pragma unroll
            for (int j = 0; j < 8; ++j) {
                int d = kg * 8 + j;
                float v = fmaf(p0, Wp[d], fmaf(p1, Wp[128 + d], fmaf(p2, Wp[256 + d], bp[d])));
                u[j] = f2b(fmaxf(v, 0.f));
            }
        } else {
#pragma unroll
            for (int j = 0; j < 8; ++j) u[j] = 0;
        }
        char* dst = (char*)feat + row * 256 + ((kg * 16) ^ ((row & 7) << 4));
        *(uint4*)dst = *(uint4*)u;
    }
    __syncthreads();
    int wid = t >> 6, l = t & 63;
    int r0 = wid * 16;
    f32x4 acc[8];
#pragma unroll
    for (int ct = 0; ct < 8; ++ct) acc[ct] = (f32x4){0.f, 0.f, 0.f, 0.f};
    const bf16x8* wp = (const bf16x8*)WpackE;
#pragma unroll
    for (int kc = 0; kc < 4; ++kc) {
        int row = r0 + (l & 15);
        const char* ap = (const char*)feat + row * 256 +
                         ((kc * 64 + ((l >> 4) * 16)) ^ ((row & 7) << 4));
        bf16x8 afrag = *(const bf16x8*)ap;
#pragma unroll
        for (int ct = 0; ct < 8; ++ct) {
            bf16x8 bfrag = wp[(ct * 4 + kc) * 64 + l];
            acc[ct] = __builtin_amdgcn_mfma_f32_16x16x32_bf16(afrag, bfrag, acc[ct], 0, 0, 0);
        }
    }
    int subrow = (l >> 4) * 4, col0 = l & 15;
    int ids[4];
#pragma unroll
    for (int i = 0; i < 4; ++i) {
        int node = base + r0 + subrow + i;
        ids[i] = (node < N_NODES) ? idfeat[node] : 0;
    }
    __syncthreads(); // all MFMA feat reads done; reuse feat as bf16 smx
#pragma unroll
    for (int ct = 0; ct < 8; ++ct) {
        int col = ct * 16 + col0;
        float bcol = bn[col];
#pragma unroll
        for (int i = 0; i < 4; ++i) {
            int node = base + r0 + subrow + i;
            unsigned short ob = 0;
            if (node < N_NODES) {
                float v = acc[ct][i] + bcol + T[ids[i] * 128 + col];
                ob = f2b(fmaxf(v, 0.f));
                A16[(size_t)node * 128 + col] = ob;
            }
            feat[(r0 + subrow + i) * 128 + col] = ob;
        }
    }
    __syncthreads();
    if (t < 128) {
        int j = 0;
        while (j < 64) {
            int g = bbat[j];
            float m = b2f(feat[j * 128 + t]);
            int k = j + 1;
            while (k < 64 && bbat[k] == g) { m = fmaxf(m, b2f(feat[k * 128 + t])); ++k; }
            if (g >= 0) atomicMax((int*)&gbuf[g * GDIM + t], __float_as_int(m));
            j = k;
        }
    }
}

// ---- fused GCN layer, 256 threads / 16 nodes, 16 lanes x 16B per row ----
// 4 independent edge streams per wave (vs 2): 2x memory-level parallelism;
// 8 blocks/CU by threads (vs 4): finer scheduling granularity.

__global__ __launch_bounds__(256) void k_layer(
    const unsigned short* __restrict__ Hin, unsigned short* __restrict__ Hout,
    const unsigned short* __restrict__ WpackL,
    const int* __restrict__ offs, const int* __restrict__ cnt,
    const unsigned int* __restrict__ csrs, const float* __restrict__ dinv,
    const float* __restrict__ bias, const int* __restrict__ batch,
    const int* __restrict__ perm, float* __restrict__ gbuf, int goff) {
    __shared__ unsigned short hagg[16 * 128]; // 4KB swizzled bf16
    __shared__ float smx[16][132];            // padded
    __shared__ int bb[16];
    __shared__ int snode[16];
    int tid = threadIdx.x;
    int wave = tid >> 6, lane = tid & 63;
    int q = lane >> 4, l16 = lane & 15;
    int row = wave * 4 + q;                   // 0..15
    int nbase = blockIdx.x * 16;              // 50000 % 16 == 0
    if (tid < 16) {
        int n = perm[nbase + tid];
        snode[tid] = n;
        bb[tid] = batch[n];
    }
    int node = perm[nbase + row];

    // ---- phase 1: aggregate in h-space; lane reads 16B (8 bf16 cols)
    int start = offs[node];
    int c = cnt[node];
    float di = dinv[node];
    float sw = di * di;
    const uint4* B4 = (const uint4*)Hin;      // 16 uint4 per 128-col bf16 row
    float a[8];
    {
        uint4 sv = B4[(size_t)node * 16 + l16];
        a[0] = sw * __uint_as_float(sv.x << 16);
        a[1] = sw * __uint_as_float(sv.x & 0xffff0000u);
        a[2] = sw * __uint_as_float(sv.y << 16);
        a[3] = sw * __uint_as_float(sv.y & 0xffff0000u);
        a[4] = sw * __uint_as_float(sv.z << 16);
        a[5] = sw * __uint_as_float(sv.z & 0xffff0000u);
        a[6] = sw * __uint_as_float(sv.w << 16);
        a[7] = sw * __uint_as_float(sv.w & 0xffff0000u);
    }
    int j = 0;
    for (; j + 8 <= c; j += 8) {
        unsigned pk[8];
        uint4 v[8];
#pragma unroll
        for (int i = 0; i < 8; ++i) pk[i] = csrs[start + j + i];
#pragma unroll
        for (int i = 0; i < 8; ++i) v[i] = B4[(size_t)(pk[i] & 0xffffu) * 16 + l16];
#pragma unroll
        for (int i = 0; i < 8; ++i) {
            float w = __uint_as_float(pk[i] & 0xffff0000u);
            a[0] = fmaf(w, __uint_as_float(v[i].x << 16), a[0]);
            a[1] = fmaf(w, __uint_as_float(v[i].x & 0xffff0000u), a[1]);
            a[2] = fmaf(w, __uint_as_float(v[i].y << 16), a[2]);
            a[3] = fmaf(w, __uint_as_float(v[i].y & 0xffff0000u), a[3]);
            a[4] = fmaf(w, __uint_as_float(v[i].z << 16), a[4]);
            a[5] = fmaf(w, __uint_as_float(v[i].z & 0xffff0000u), a[5]);
            a[6] = fmaf(w, __uint_as_float(v[i].w << 16), a[6]);
            a[7] = fmaf(w, __uint_as_float(v[i].w & 0xffff0000u), a[7]);
        }
    }
    for (; j < c; ++j) {
        unsigned pk = csrs[start + j];
        float w = __uint_as_float(pk & 0xffff0000u);
        uint4 v = B4[(size_t)(pk & 0xffffu) * 16 + l16];
        a[0] = fmaf(w, __uint_as_float(v.x << 16), a[0]);
        a[1] = fmaf(w, __uint_as_float(v.x & 0xffff0000u), a[1]);
        a[2] = fmaf(w, __uint_as_float(v.y << 16), a[2]);
        a[3] = fmaf(w, __uint_as_float(v.y & 0xffff0000u), a[3]);
        a[4] = fmaf(w, __uint_as_float(v.z << 16), a[4]);
        a[5] = fmaf(w, __uint_as_float(v.z & 0xffff0000u), a[5]);
        a[6] = fmaf(w, __uint_as_float(v.w << 16), a[6]);
        a[7] = fmaf(w, __uint_as_float(v.w & 0xffff0000u), a[7]);
    }
    {
        unsigned u[4];
#pragma unroll
        for (int k = 0; k < 4; ++k)
            u[k] = (unsigned)f2b(a[2 * k]) | ((unsigned)f2b(a[2 * k + 1]) << 16);
        char* dst = (char*)hagg + row * 256 + ((l16 * 16) ^ ((row & 7) << 4));
        *(uint4*)dst = *(uint4*)u;
    }
    __syncthreads();

    // ---- phase 2: MFMA 16x128 @ 128x128; wave covers 2 col tiles
    f32x4 oacc[2] = {(f32x4){0.f, 0.f, 0.f, 0.f}, (f32x4){0.f, 0.f, 0.f, 0.f}};
    const bf16x8* wp = (const bf16x8*)WpackL;
#pragma unroll
    for (int kc = 0; kc < 4; ++kc) {
        int arow = lane & 15;
        const char* ap = (const char*)hagg + arow * 256 +
                         ((kc * 64 + ((lane >> 4) * 16)) ^ ((arow & 7) << 4));
        bf16x8 afrag = *(const bf16x8*)ap;
#pragma unroll
        for (int ci = 0; ci < 2; ++ci) {
            int ct = wave * 2 + ci;
            bf16x8 bfrag = wp[(ct * 4 + kc) * 64 + lane];
            oacc[ci] = __builtin_amdgcn_mfma_f32_16x16x32_bf16(afrag, bfrag, oacc[ci], 0, 0, 0);
        }
    }

    // ---- phase 3: bias + relu + store + fused segmax
    int subrow = (lane >> 4) * 4;
#pragma unroll
    for (int ci = 0; ci < 2; ++ci) {
        int col = (wave * 2 + ci) * 16 + (lane & 15);
        float bcol = bias[col];
#pragma unroll
        for (int i = 0; i < 4; ++i) {
            int r = subrow + i;
            float v = fmaxf(oacc[ci][i] + bcol, 0.f);
            smx[r][col] = v;
            Hout[(size_t)snode[r] * 128 + col] = f2b(v);
        }
    }
    __syncthreads();
    if (tid < 128) {
        int jj = 0;
        while (jj < 16) {
            int g = bb[jj];
            float m = smx[jj][tid];
            int k = jj + 1;
            while (k < 16 && bb[k] == g) { m = fmaxf(m, smx[k][tid]); ++k; }
            atomicMax((int*)&gbuf[g * GDIM + goff + tid], __float_as_int(m));
            jj = k;
        }
    }
}

// ---- final: out[G,128] = gbuf[G,640] @ Wa[640,128] + ba

__global__ __launch_bounds__(128) void k_final(const float* __restrict__ gbuf,
                                               const float* __restrict__ Wa,
                                               const float* __restrict__ ba,
                                               float* __restrict__ out) {
    __shared__ float gr[GDIM];
    int g = blockIdx.x, t = threadIdx.x;
    for (int i = t; i < GDIM; i += 128) gr[i] = gbuf[g * GDIM + i];
    __syncthreads();
    float acc = ba[t];
    for (int k = 0; k < GDIM; ++k) acc = fmaf(gr[k], Wa[k * 128 + t], acc);
    out[g * 128 + t] = acc;
}

// ---- launch ----

extern "C" void kernel_launch(void* const* d_in, const int* in_sizes, int n_in,
                              void* d_out, int out_size, void* d_ws, size_t ws_size,
                              hipStream_t stream) {
    const float* pos    = (const float*)d_in[0];
    const int*   idfeat = (const int*)d_in[1];
    const int*   eidx   = (const int*)d_in[2];
    const int*   batch  = (const int*)d_in[3];
    const float* Wp     = (const float*)d_in[5];
    const float* bp     = (const float*)d_in[6];
    const float* id_emb = (const float*)d_in[7];
    const float* Wn     = (const float*)d_in[8];
    const float* bn     = (const float*)d_in[9];
    const float* convW  = (const float*)d_in[10];
    const float* convb  = (const float*)d_in[11];
    const float* Wa     = (const float*)d_in[12];
    const float* ba     = (const float*)d_in[13];
    float* out = (float*)d_out;

    const int* esrc = eidx;
    const int* edst = eidx + N_EDGES;

    char* w = (char*)d_ws;
    auto alloc = [&](size_t bytes) -> char* {
        char* p = w;
        w += (bytes + 255) & ~(size_t)255;
        return p;
    };
    // zero region: cnt + gbuf + hist2 + bcnt_rel (single memset)
    char* zstart = w;
    int*   cnt      = (int*)alloc((size_t)N_NODES * 4);
    float* gbuf     = (float*)alloc((size_t)NGRAPH * GDIM * 4);
    int*   hist2    = (int*)alloc((size_t)16384 * 4);
    int*   bcnt_rel = (int*)alloc((size_t)NBUCK * 4);
    size_t zbytes = (size_t)(w - zstart);

    unsigned short* A16a = (unsigned short*)alloc((size_t)N_NODES * D * 2);
    unsigned short* A16b = (unsigned short*)alloc((size_t)N_NODES * D * 2);
    float* dinv = (float*)alloc((size_t)N_NODES * 4);
    int*   offs = (int*)alloc((size_t)(N_NODES + 1) * 4);
    int*   csum = (int*)alloc(64 * 4);
    int*   coff = (int*)alloc(64 * 4);
    unsigned int* csrs = (unsigned int*)alloc((size_t)N_EDGES * 4);
    int*   ebuf = (int*)alloc((size_t)NBUCK * BCAP * 4);
    int*   perm = (int*)alloc((size_t)N_NODES * 4);
    float* T    = (float*)alloc((size_t)256 * D * 4);
    unsigned short* Wpack = (unsigned short*)alloc((size_t)5 * 16384 * 2);

    hipMemsetAsync(zstart, 0, zbytes, stream);

    k_bucket<<<(N_EDGES + 2047) / 2048, 256, 0, stream>>>(esrc, edst, cnt, bcnt_rel, ebuf);

    int nchunk = (N_NODES + 1023) / 1024; // 49
    k_scanA<<<nchunk, 256, 0, stream>>>(cnt, offs, csum);
    k_scanB<<<1, 64, 0, stream>>>(csum, coff, nchunk);
    k_scanC<<<(N_NODES + 255) / 256, 256, 0, stream>>>(offs, coff, cnt, dinv, batch, hist2);
    k_scan16k<<<1, 1024, 0, stream>>>(hist2);
    k_scatter<<<(N_NODES + 255) / 256, 256, 0, stream>>>(cnt, batch, hist2, perm);

    k_fillB<<<NBUCK, 256, 0, stream>>>(ebuf, bcnt_rel, offs, dinv, csrs);

    k_prep<<<448, 256, 0, stream>>>(Wn, convW, Wpack, id_emb, T);
    k_encoder<<<(N_NODES + 63) / 64, 256, 0, stream>>>(pos, idfeat, Wp, bp, Wpack, bn, T,
                                                       A16a, batch, gbuf);

    unsigned short* Hin = A16a;
    unsigned short* Hout = A16b;
    for (int l = 0; l < NLAYER; ++l) {
        k_layer<<<N_NODES / 16, 256, 0, stream>>>(Hin, Hout, Wpack + (size_t)(l + 1) * 16384,
                                                  offs, cnt, csrs, dinv,
                                                  convb + (size_t)l * D, batch, perm, gbuf,
                                                  (l + 1) * D);
        unsigned short* tmp = Hin; Hin = Hout; Hout = tmp;
    }

    k_final<<<NGRAPH, 128, 0, stream>>>(gbuf, Wa, ba, out);
}

// Round 13
// 260.713 us; speedup vs baseline: 1.1466x; 1.0782x over previous
//
#include <hip/hip_runtime.h>

#define N_NODES 50000
#define N_EDGES 800000
#define D 128
#define NLAYER 4
#define NGRAPH 128
#define GDIM (5 * D) // 640
#define NBUCK 196    // dst>>8 buckets
#define BCAP 4608    // fixed bucket capacity (mean 4096 -> +8 sigma)

typedef __attribute__((ext_vector_type(8))) short bf16x8;
typedef __attribute__((ext_vector_type(4))) float f32x4;

__device__ __forceinline__ float b2f(unsigned short u) {
    return __uint_as_float(((unsigned)u) << 16);
}
__device__ __forceinline__ unsigned short f2b(float f) {
    unsigned u = __float_as_uint(f);
    unsigned r = (u + 0x7fffu + ((u >> 16) & 1u)) >> 16; // round-to-nearest-even
    return (unsigned short)r;
}

// ---- Pass A: bucket edges by dst>>8 into fixed-capacity bucket-major ebuf
// (packed src | ((dst&255)<<16)). NO global per-node atomics.

__global__ __launch_bounds__(256) void k_bucket(
    const int* __restrict__ esrc, const int* __restrict__ edst,
    int* __restrict__ bcnt_rel, int* __restrict__ ebuf) {
    __shared__ int hcnt[NBUCK];
    __shared__ int hbase[NBUCK];
    int t = threadIdx.x;
    for (int i = t; i < NBUCK; i += 256) hcnt[i] = 0;
    __syncthreads();
    int e0 = blockIdx.x * 1024 + t;
    int d[4], s[4];
#pragma unroll
    for (int i = 0; i < 4; ++i) {
        int e = e0 + i * 256;
        if (e < N_EDGES) {
            d[i] = edst[e];
            s[i] = esrc[e];
            atomicAdd(&hcnt[d[i] >> 8], 1);
        } else {
            d[i] = -1;
        }
    }
    __syncthreads();
    for (int i = t; i < NBUCK; i += 256) {
        int c = hcnt[i];
        hbase[i] = (c > 0) ? (i * BCAP + atomicAdd(&bcnt_rel[i], c)) : 0;
        hcnt[i] = 0;
    }
    __syncthreads();
#pragma unroll
    for (int i = 0; i < 4; ++i) {
        if (d[i] >= 0) {
            int b = d[i] >> 8;
            int p = atomicAdd(&hcnt[b], 1);
            int pos = hbase[b] + p;
            if (pos < (b + 1) * BCAP)
                ebuf[pos] = (s[i] & 0xffff) | ((d[i] & 255) << 16);
        }
    }
}

// ---- exclusive scan of the 196 bucket totals -> bbase ----

__global__ void k_bscan(const int* __restrict__ bcnt_rel, int* __restrict__ bbase) {
    __shared__ int lds[256];
    int t = threadIdx.x;
    int v = (t < NBUCK) ? bcnt_rel[t] : 0;
    lds[t] = v;
    __syncthreads();
    int tot = v;
    for (int off = 1; off < 256; off <<= 1) {
        int add = (t >= off) ? lds[t - off] : 0;
        __syncthreads();
        tot += add;
        lds[t] = tot;
        __syncthreads();
    }
    if (t < NBUCK) bbase[t] = tot - v;
}

// ---- fillB1: per bucket, count own 256 dsts from bucketed edges, LDS-scan ->
// offs/cnt/dinv + (batch,deg) histogram. Replaces k_count + 50k scan chain.

__global__ __launch_bounds__(256) void k_fillB1(
    const int* __restrict__ ebuf, const int* __restrict__ bcnt_rel,
    const int* __restrict__ bbase, const int* __restrict__ batch,
    int* __restrict__ offs, int* __restrict__ cnt, float* __restrict__ dinv,
    int* __restrict__ hist2) {
    __shared__ int lcnt[256];
    __shared__ int lscan[256];
    int b = blockIdx.x, t = threadIdx.x;
    lcnt[t] = 0;
    __syncthreads();
    int s0 = b * BCAP, s1 = b * BCAP + bcnt_rel[b];
    for (int i = s0 + t; i < s1; i += 256)
        atomicAdd(&lcnt[(ebuf[i] >> 16) & 255], 1);
    __syncthreads();
    int v = lcnt[t];
    lscan[t] = v;
    __syncthreads();
    int tot = v;
    for (int off = 1; off < 256; off <<= 1) {
        int add = (t >= off) ? lscan[t - off] : 0;
        __syncthreads();
        tot += add;
        lscan[t] = tot;
        __syncthreads();
    }
    int node = (b << 8) + t;
    if (node < N_NODES) {
        offs[node] = bbase[b] + (tot - v);
        cnt[node] = v;
        dinv[node] = 1.f / sqrtf((float)(v + 1)); // +1 self-loop
        atomicAdd(&hist2[batch[node] * 128 + min(v, 127)], 1);
    }
}

// ---- fillB2: scatter weighted CSR entries within the bucket window ----
// Entry = src | (bf16(dinv[src]*dinv[dst]) << 16).

__global__ __launch_bounds__(256) void k_fillB2(
    const int* __restrict__ ebuf, const int* __restrict__ bcnt_rel,
    const int* __restrict__ offs, const float* __restrict__ dinv,
    unsigned int* __restrict__ csrs) {
    __shared__ int loffs[256];
    __shared__ int lcnt[256];
    __shared__ float ldinv[256];
    int b = blockIdx.x, t = threadIdx.x;
    int nbase = b << 8;
    if (nbase + t < N_NODES) {
        loffs[t] = offs[nbase + t];
        ldinv[t] = dinv[nbase + t];
    }
    lcnt[t] = 0;
    __syncthreads();
    int s0 = b * BCAP, s1 = b * BCAP + bcnt_rel[b];
    for (int i = s0 + t; i < s1; i += 256) {
        int pk = ebuf[i];
        int ld = (pk >> 16) & 255;
        int src = pk & 0xffff;
        float w = dinv[src] * ldinv[ld];
        int p = atomicAdd(&lcnt[ld], 1);
        csrs[loffs[ld] + p] = (unsigned)src | ((unsigned)f2b(w) << 16);
    }
}

// in-place exclusive scan of 16384 bins (1 block, 1024 threads x 16)
__global__ __launch_bounds__(1024) void k_scan16k(int* __restrict__ hist2) {
    __shared__ int lds[1024];
    int t = threadIdx.x;
    int v[16];
    int s = 0;
#pragma unroll
    for (int j = 0; j < 16; ++j) { v[j] = hist2[t * 16 + j]; s += v[j]; }
    lds[t] = s;
    __syncthreads();
    int tot = s;
    for (int off = 1; off < 1024; off <<= 1) {
        int add = (t >= off) ? lds[t - off] : 0;
        __syncthreads();
        tot += add;
        lds[t] = tot;
        __syncthreads();
    }
    int run = tot - s;
#pragma unroll
    for (int j = 0; j < 16; ++j) { hist2[t * 16 + j] = run; run += v[j]; }
}

// scatter node ids into (batch, degree)-sorted perm
__global__ void k_scatter(const int* __restrict__ cnt, const int* __restrict__ batch,
                          int* __restrict__ hist2, int* __restrict__ perm) {
    int i = blockIdx.x * 256 + threadIdx.x;
    if (i < N_NODES) {
        int key = batch[i] * 128 + min(cnt[i], 127);
        int p = atomicAdd(&hist2[key], 1);
        perm[p] = i;
    }
}

// ---- prep: Wpack (blocks 0..319) + T = relu(id_emb)@Wn_bot (320..447)

__global__ __launch_bounds__(256) void k_prep(
    const float* __restrict__ Wn, const float* __restrict__ convW,
    unsigned short* __restrict__ Wpack,
    const float* __restrict__ id_emb, float* __restrict__ T) {
    int blk = blockIdx.x;
    if (blk < 320) {
        int tid = blk * 256 + threadIdx.x;
        int m = tid >> 14;
        int rem = tid & 16383;
        int ct = rem >> 11, kc = (rem >> 9) & 3, l = (rem >> 3) & 63, j = rem & 7;
        int k = kc * 32 + ((l >> 4) * 8) + j;
        int n = ct * 16 + (l & 15);
        const float* src = (m == 0) ? Wn : (convW + (size_t)(m - 1) * 16384);
        Wpack[tid] = f2b(src[k * 128 + n]);
    } else {
        int t = threadIdx.x;
        int d = t & 127;
        int r = (blk - 320) * 2 + (t >> 7);
        float acc = 0.f;
        for (int k = 0; k < 128; ++k)
            acc = fmaf(fmaxf(id_emb[r * 128 + k], 0.f), Wn[(128 + k) * 128 + d], acc);
        T[r * 128 + d] = acc;
    }
}

// ---- MFMA encoder + fused segmax (layer 0, original node order) ----

__global__ __launch_bounds__(256) void k_encoder(
    const float* __restrict__ pos, const int* __restrict__ idfeat,
    const float* __restrict__ Wp, const float* __restrict__ bp,
    const unsigned short* __restrict__ WpackE, const float* __restrict__ bn,
    const float* __restrict__ T, unsigned short* __restrict__ A16,
    const int* __restrict__ batch, float* __restrict__ gbuf) {
    __shared__ unsigned short feat[64 * 128]; // 16KB, swizzled; reused as smx
    __shared__ float posl[192];
    __shared__ int bbat[64];
    int t = threadIdx.x;
    int base = blockIdx.x * 64;
    int avail = N_NODES - base;
    if (t < 192) {
        int idx = base * 3 + t;
        posl[t] = (idx < N_NODES * 3) ? pos[idx] : 0.f;
    }
    if (t < 64) bbat[t] = (base + t < N_NODES) ? batch[base + t] : -1;
    __syncthreads();
#pragma unroll
    for (int i = 0; i < 4; ++i) {
        int gid = t + i * 256;
        int row = gid >> 4, kg = gid & 15;
        unsigned short u[8];
        if (row < avail) {
            float p0 = posl[row * 3], p1 = posl[row * 3 + 1], p2 = posl[row * 3 + 2];
#pragma unroll
            for (int j = 0; j < 8; ++j) {
                int d = kg * 8 + j;
                float v = fmaf(p0, Wp[d], fmaf(p1, Wp[128 + d], fmaf(p2, Wp[256 + d], bp[d])));
                u[j] = f2b(fmaxf(v, 0.f));
            }
        } else {
#pragma unroll
            for (int j = 0; j < 8; ++j) u[j] = 0;
        }
        char* dst = (char*)feat + row * 256 + ((kg * 16) ^ ((row & 7) << 4));
        *(uint4*)dst = *(uint4*)u;
    }
    __syncthreads();
    int wid = t >> 6, l = t & 63;
    int r0 = wid * 16;
    f32x4 acc[8];
#pragma unroll
    for (int ct = 0; ct < 8; ++ct) acc[ct] = (f32x4){0.f, 0.f, 0.f, 0.f};
    const bf16x8* wp = (const bf16x8*)WpackE;
#pragma unroll
    for (int kc = 0; kc < 4; ++kc) {
        int row = r0 + (l & 15);
        const char* ap = (const char*)feat + row * 256 +
                         ((kc * 64 + ((l >> 4) * 16)) ^ ((row & 7) << 4));
        bf16x8 afrag = *(const bf16x8*)ap;
#pragma unroll
        for (int ct = 0; ct < 8; ++ct) {
            bf16x8 bfrag = wp[(ct * 4 + kc) * 64 + l];
            acc[ct] = __builtin_amdgcn_mfma_f32_16x16x32_bf16(afrag, bfrag, acc[ct], 0, 0, 0);
        }
    }
    int subrow = (l >> 4) * 4, col0 = l & 15;
    int ids[4];
#pragma unroll
    for (int i = 0; i < 4; ++i) {
        int node = base + r0 + subrow + i;
        ids[i] = (node < N_NODES) ? idfeat[node] : 0;
    }
    __syncthreads(); // all MFMA feat reads done; reuse feat as bf16 smx
#pragma unroll
    for (int ct = 0; ct < 8; ++ct) {
        int col = ct * 16 + col0;
        float bcol = bn[col];
#pragma unroll
        for (int i = 0; i < 4; ++i) {
            int node = base + r0 + subrow + i;
            unsigned short ob = 0;
            if (node < N_NODES) {
                float v = acc[ct][i] + bcol + T[ids[i] * 128 + col];
                ob = f2b(fmaxf(v, 0.f));
                A16[(size_t)node * 128 + col] = ob;
            }
            feat[(r0 + subrow + i) * 128 + col] = ob;
        }
    }
    __syncthreads();
    if (t < 128) {
        int j = 0;
        while (j < 64) {
            int g = bbat[j];
            float m = b2f(feat[j * 128 + t]);
            int k = j + 1;
            while (k < 64 && bbat[k] == g) { m = fmaxf(m, b2f(feat[k * 128 + t])); ++k; }
            if (g >= 0) atomicMax((int*)&gbuf[g * GDIM + t], __float_as_int(m));
            j = k;
        }
    }
}

// ---- fused GCN layer, 256 threads / 16 nodes, 16 lanes x 16B per row ----

__global__ __launch_bounds__(256) void k_layer(
    const unsigned short* __restrict__ Hin, unsigned short* __restrict__ Hout,
    const unsigned short* __restrict__ WpackL,
    const int* __restrict__ offs, const int* __restrict__ cnt,
    const unsigned int* __restrict__ csrs, const float* __restrict__ dinv,
    const float* __restrict__ bias, const int* __restrict__ batch,
    const int* __restrict__ perm, float* __restrict__ gbuf, int goff) {
    __shared__ unsigned short hagg[16 * 128]; // 4KB swizzled bf16
    __shared__ float smx[16][132];            // padded
    __shared__ int bb[16];
    __shared__ int snode[16];
    int tid = threadIdx.x;
    int wave = tid >> 6, lane = tid & 63;
    int q = lane >> 4, l16 = lane & 15;
    int row = wave * 4 + q;                   // 0..15
    int nbase = blockIdx.x * 16;              // 50000 % 16 == 0
    if (tid < 16) {
        int n = perm[nbase + tid];
        snode[tid] = n;
        bb[tid] = batch[n];
    }
    int node = perm[nbase + row];

    // ---- phase 1: aggregate in h-space; lane reads 16B (8 bf16 cols)
    int start = offs[node];
    int c = cnt[node];
    float di = dinv[node];
    float sw = di * di;
    const uint4* B4 = (const uint4*)Hin;      // 16 uint4 per 128-col bf16 row
    float a[8];
    {
        uint4 sv = B4[(size_t)node * 16 + l16];
        a[0] = sw * __uint_as_float(sv.x << 16);
        a[1] = sw * __uint_as_float(sv.x & 0xffff0000u);
        a[2] = sw * __uint_as_float(sv.y << 16);
        a[3] = sw * __uint_as_float(sv.y & 0xffff0000u);
        a[4] = sw * __uint_as_float(sv.z << 16);
        a[5] = sw * __uint_as_float(sv.z & 0xffff0000u);
        a[6] = sw * __uint_as_float(sv.w << 16);
        a[7] = sw * __uint_as_float(sv.w & 0xffff0000u);
    }
    int j = 0;
    for (; j + 8 <= c; j += 8) {
        unsigned pk[8];
        uint4 v[8];
#pragma unroll
        for (int i = 0; i < 8; ++i) pk[i] = csrs[start + j + i];
#pragma unroll
        for (int i = 0; i < 8; ++i) v[i] = B4[(size_t)(pk[i] & 0xffffu) * 16 + l16];
#pragma unroll
        for (int i = 0; i < 8; ++i) {
            float w = __uint_as_float(pk[i] & 0xffff0000u);
            a[0] = fmaf(w, __uint_as_float(v[i].x << 16), a[0]);
            a[1] = fmaf(w, __uint_as_float(v[i].x & 0xffff0000u), a[1]);
            a[2] = fmaf(w, __uint_as_float(v[i].y << 16), a[2]);
            a[3] = fmaf(w, __uint_as_float(v[i].y & 0xffff0000u), a[3]);
            a[4] = fmaf(w, __uint_as_float(v[i].z << 16), a[4]);
            a[5] = fmaf(w, __uint_as_float(v[i].z & 0xffff0000u), a[5]);
            a[6] = fmaf(w, __uint_as_float(v[i].w << 16), a[6]);
            a[7] = fmaf(w, __uint_as_float(v[i].w & 0xffff0000u), a[7]);
        }
    }
    for (; j < c; ++j) {
        unsigned pk = csrs[start + j];
        float w = __uint_as_float(pk & 0xffff0000u);
        uint4 v = B4[(size_t)(pk & 0xffffu) * 16 + l16];
        a[0] = fmaf(w, __uint_as_float(v.x << 16), a[0]);
        a[1] = fmaf(w, __uint_as_float(v.x & 0xffff0000u), a[1]);
        a[2] = fmaf(w, __uint_as_float(v.y << 16), a[2]);
        a[3] = fmaf(w, __uint_as_float(v.y & 0xffff0000u), a[3]);
        a[4] = fmaf(w, __uint_as_float(v.z << 16), a[4]);
        a[5] = fmaf(w, __uint_as_float(v.z & 0xffff0000u), a[5]);
        a[6] = fmaf(w, __uint_as_float(v.w << 16), a[6]);
        a[7] = fmaf(w, __uint_as_float(v.w & 0xffff0000u), a[7]);
    }
    {
        unsigned u[4];
#pragma unroll
        for (int k = 0; k < 4; ++k)
            u[k] = (unsigned)f2b(a[2 * k]) | ((unsigned)f2b(a[2 * k + 1]) << 16);
        char* dst = (char*)hagg + row * 256 + ((l16 * 16) ^ ((row & 7) << 4));
        *(uint4*)dst = *(uint4*)u;
    }
    __syncthreads();

    // ---- phase 2: MFMA 16x128 @ 128x128; wave covers 2 col tiles
    f32x4 oacc[2] = {(f32x4){0.f, 0.f, 0.f, 0.f}, (f32x4){0.f, 0.f, 0.f, 0.f}};
    const bf16x8* wp = (const bf16x8*)WpackL;
#pragma unroll
    for (int kc = 0; kc < 4; ++kc) {
        int arow = lane & 15;
        const char* ap = (const char*)hagg + arow * 256 +
                         ((kc * 64 + ((lane >> 4) * 16)) ^ ((arow & 7) << 4));
        bf16x8 afrag = *(const bf16x8*)ap;
#pragma unroll
        for (int ci = 0; ci < 2; ++ci) {
            int ct = wave * 2 + ci;
            bf16x8 bfrag = wp[(ct * 4 + kc) * 64 + lane];
            oacc[ci] = __builtin_amdgcn_mfma_f32_16x16x32_bf16(afrag, bfrag, oacc[ci], 0, 0, 0);
        }
    }

    // ---- phase 3: bias + relu + store + fused segmax
    int subrow = (lane >> 4) * 4;
#pragma unroll
    for (int ci = 0; ci < 2; ++ci) {
        int col = (wave * 2 + ci) * 16 + (lane & 15);
        float bcol = bias[col];
#pragma unroll
        for (int i = 0; i < 4; ++i) {
            int r = subrow + i;
            float v = fmaxf(oacc[ci][i] + bcol, 0.f);
            smx[r][col] = v;
            Hout[(size_t)snode[r] * 128 + col] = f2b(v);
        }
    }
    __syncthreads();
    if (tid < 128) {
        int jj = 0;
        while (jj < 16) {
            int g = bb[jj];
            float m = smx[jj][tid];
            int k = jj + 1;
            while (k < 16 && bb[k] == g) { m = fmaxf(m, smx[k][tid]); ++k; }
            atomicMax((int*)&gbuf[g * GDIM + goff + tid], __float_as_int(m));
            jj = k;
        }
    }
}

// ---- final: out[G,128] = gbuf[G,640] @ Wa[640,128] + ba

__global__ __launch_bounds__(128) void k_final(const float* __restrict__ gbuf,
                                               const float* __restrict__ Wa,
                                               const float* __restrict__ ba,
                                               float* __restrict__ out) {
    __shared__ float gr[GDIM];
    int g = blockIdx.x, t = threadIdx.x;
    for (int i = t; i < GDIM; i += 128) gr[i] = gbuf[g * GDIM + i];
    __syncthreads();
    float acc = ba[t];
    for (int k = 0; k < GDIM; ++k) acc = fmaf(gr[k], Wa[k * 128 + t], acc);
    out[g * 128 + t] = acc;
}

// ---- launch ----

extern "C" void kernel_launch(void* const* d_in, const int* in_sizes, int n_in,
                              void* d_out, int out_size, void* d_ws, size_t ws_size,
                              hipStream_t stream) {
    const float* pos    = (const float*)d_in[0];
    const int*   idfeat = (const int*)d_in[1];
    const int*   eidx   = (const int*)d_in[2];
    const int*   batch  = (const int*)d_in[3];
    const float* Wp     = (const float*)d_in[5];
    const float* bp     = (const float*)d_in[6];
    const float* id_emb = (const float*)d_in[7];
    const float* Wn     = (const float*)d_in[8];
    const float* bn     = (const float*)d_in[9];
    const float* convW  = (const float*)d_in[10];
    const float* convb  = (const float*)d_in[11];
    const float* Wa     = (const float*)d_in[12];
    const float* ba     = (const float*)d_in[13];
    float* out = (float*)d_out;

    const int* esrc = eidx;
    const int* edst = eidx + N_EDGES;

    char* w = (char*)d_ws;
    auto alloc = [&](size_t bytes) -> char* {
        char* p = w;
        w += (bytes + 255) & ~(size_t)255;
        return p;
    };
    // zero region: gbuf + hist2 + bcnt_rel (single memset)
    char* zstart = w;
    float* gbuf     = (float*)alloc((size_t)NGRAPH * GDIM * 4);
    int*   hist2    = (int*)alloc((size_t)16384 * 4);
    int*   bcnt_rel = (int*)alloc((size_t)NBUCK * 4);
    size_t zbytes = (size_t)(w - zstart);

    int*   cnt  = (int*)alloc((size_t)N_NODES * 4);
    unsigned short* A16a = (unsigned short*)alloc((size_t)N_NODES * D * 2);
    unsigned short* A16b = (unsigned short*)alloc((size_t)N_NODES * D * 2);
    float* dinv = (float*)alloc((size_t)N_NODES * 4);
    int*   offs = (int*)alloc((size_t)(N_NODES + 1) * 4);
    int*   bbase= (int*)alloc((NBUCK + 1) * 4);
    unsigned int* csrs = (unsigned int*)alloc((size_t)N_EDGES * 4);
    int*   ebuf = (int*)alloc((size_t)NBUCK * BCAP * 4);
    int*   perm = (int*)alloc((size_t)N_NODES * 4);
    float* T    = (float*)alloc((size_t)256 * D * 4);
    unsigned short* Wpack = (unsigned short*)alloc((size_t)5 * 16384 * 2);

    hipMemsetAsync(zstart, 0, zbytes, stream);

    k_bucket<<<(N_EDGES + 1023) / 1024, 256, 0, stream>>>(esrc, edst, bcnt_rel, ebuf);
    k_bscan<<<1, 256, 0, stream>>>(bcnt_rel, bbase);
    k_fillB1<<<NBUCK, 256, 0, stream>>>(ebuf, bcnt_rel, bbase, batch, offs, cnt, dinv, hist2);
    k_scan16k<<<1, 1024, 0, stream>>>(hist2);
    k_scatter<<<(N_NODES + 255) / 256, 256, 0, stream>>>(cnt, batch, hist2, perm);
    k_fillB2<<<NBUCK, 256, 0, stream>>>(ebuf, bcnt_rel, offs, dinv, csrs);

    k_prep<<<448, 256, 0, stream>>>(Wn, convW, Wpack, id_emb, T);
    k_encoder<<<(N_NODES + 63) / 64, 256, 0, stream>>>(pos, idfeat, Wp, bp, Wpack, bn, T,
                                                       A16a, batch, gbuf);

    unsigned short* Hin = A16a;
    unsigned short* Hout = A16b;
    for (int l = 0; l < NLAYER; ++l) {
        k_layer<<<N_NODES / 16, 256, 0, stream>>>(Hin, Hout, Wpack + (size_t)(l + 1) * 16384,
                                                  offs, cnt, csrs, dinv,
                                                  convb + (size_t)l * D, batch, perm, gbuf,
                                                  (l + 1) * D);
        unsigned short* tmp = Hin; Hin = Hout; Hout = tmp;
    }

    k_final<<<NGRAPH, 128, 0, stream>>>(gbuf, Wa, ba, out);
}